// Round 15
// baseline (325.595 us; speedup 1.0000x reference)
//
#include <hip/hip_runtime.h>
#include <hip/hip_bf16.h>
#include <stdint.h>

#define NB 8
#define NC 64
#define NN 4096
#define NK 16
#define NO 64
#define TILE 64
#define NCHUNK 2
#define CHCOLS (NN / NCHUNK)     // 2048
#define NTILES (CHCOLS / TILE)   // 32
#define NKL 16                   // per-lane guarded candidate list
#define NKC 32                   // candidates per row for rescore (2 x 16)

typedef __attribute__((ext_vector_type(8))) short bf16x8;
typedef __attribute__((ext_vector_type(4))) float f32x4;

__device__ __forceinline__ unsigned umin32(unsigned a, unsigned b) { return a < b ? a : b; }
__device__ __forceinline__ unsigned umax32(unsigned a, unsigned b) { return a > b ? a : b; }
__device__ __forceinline__ unsigned shflx(unsigned v, int m) {
  return (unsigned)__shfl_xor((int)v, m);
}
// order-preserving fp32 -> uint map
__device__ __forceinline__ unsigned fmap(float x) {
  unsigned u = __float_as_uint(x);
  return u ^ ((unsigned)((int)u >> 31) | 0x80000000u);
}
__device__ __forceinline__ float bf2f(unsigned short h) {
  return __bfloat162float(*reinterpret_cast<__hip_bfloat16*>(&h));
}
__device__ __forceinline__ unsigned short f2bfu(float v) {
  __hip_bfloat16 hh = __float2bfloat16(v);
  return *reinterpret_cast<unsigned short*>(&hh);
}

// ---------------------------------------------------------------------------
// Kernel 1 (R13/R14-proven): projections + norms + fp32 XT + bf16 H.
// PQb[b][n] (192 u16): [0..63] = P1+bias, [64+2o] = P2[o], [64+2o+1] = Q2[o].
// ---------------------------------------------------------------------------
__global__ __launch_bounds__(256) void proj_kernel(
    const float* __restrict__ x, const float* __restrict__ We,
    const float* __restrict__ be, const float* __restrict__ Wa,
    unsigned short* __restrict__ PQb, float* __restrict__ sq,
    float* __restrict__ XT, unsigned short* __restrict__ H)
{
  __shared__ float xs[NC][TILE];
  __shared__ float wt[NC][192];
  const int bid = blockIdx.x;
  const int b   = bid >> 6;
  const int n0  = (bid & 63) * TILE;
  const int tid = threadIdx.x;

  const float4* xg4 = (const float4*)x;
  float4* xs4 = (float4*)xs;
  for (int i = tid; i < NC * TILE / 4; i += 256) {
    int c = i >> 4, p4 = i & 15;
    xs4[c * 16 + p4] = xg4[(b * NC + c) * (NN / 4) + (n0 >> 2) + p4];
  }
  for (int i = tid; i < 64 * NC; i += 256) {
    int o = i >> 6, c = i & 63;
    float w1 = We[o * 128 + c], w2 = We[o * 128 + 64 + c];
    wt[c][o]        = w1 - w2;
    wt[c][64 + o]   = w2;
    wt[c][128 + o]  = Wa[o * 128 + 64 + c];
  }
  __syncthreads();

  {
    const int p = tid & 63, cg = tid >> 6;
    union { float4 v4[4]; float f[16]; } vv;
    #pragma unroll
    for (int g = 0; g < 4; ++g) {
      vv.v4[g].x = xs[cg * 16 + g * 4 + 0][p];
      vv.v4[g].y = xs[cg * 16 + g * 4 + 1][p];
      vv.v4[g].z = xs[cg * 16 + g * 4 + 2][p];
      vv.v4[g].w = xs[cg * 16 + g * 4 + 3][p];
    }
    float4* Xp = (float4*)(XT + ((size_t)(b * NN + n0 + p) * NC + cg * 16));
    Xp[0] = vv.v4[0]; Xp[1] = vv.v4[1]; Xp[2] = vv.v4[2]; Xp[3] = vv.v4[3];
    union { unsigned short h[16]; uint4 u[2]; } hs;
    #pragma unroll
    for (int i = 0; i < 16; ++i) hs.h[i] = f2bfu(vv.f[i]);
    uint4* Hp = (uint4*)(H + ((size_t)(b * NN + n0 + p) * NC + cg * 16));
    Hp[0] = hs.u[0]; Hp[1] = hs.u[1];
  }

  if (tid >= 192) {
    int p = tid - 192;
    float s = 0.f;
    #pragma unroll
    for (int c = 0; c < NC; ++c) { float v = xs[c][p]; s = fmaf(v, v, s); }
    sq[b * NN + n0 + p] = s;
  } else {
    const int r = tid;
    float wreg[NC];
    #pragma unroll
    for (int c = 0; c < NC; ++c) wreg[c] = wt[c][r];
    const float bias = (r < 64) ? be[r] : 0.f;
    const int ridx = (r < 64) ? r
                   : (r < 128) ? (64 + 2 * (r - 64))
                               : (64 + 2 * (r - 128) + 1);
    for (int p = 0; p < TILE; p += 4) {
      float a0 = bias, a1 = bias, a2 = bias, a3 = bias;
      #pragma unroll
      for (int c = 0; c < NC; ++c) {
        float4 xv = *(const float4*)&xs[c][p];
        a0 = fmaf(wreg[c], xv.x, a0);
        a1 = fmaf(wreg[c], xv.y, a1);
        a2 = fmaf(wreg[c], xv.z, a2);
        a3 = fmaf(wreg[c], xv.w, a3);
      }
      size_t base = (size_t)(b * NN + n0 + p) * 192 + ridx;
      PQb[base]           = f2bfu(a0);
      PQb[base + 192]     = f2bfu(a1);
      PQb[base + 2*192]   = f2bfu(a2);
      PQb[base + 3*192]   = f2bfu(a3);
    }
  }
}

// ---------------------------------------------------------------------------
// Kernel 2: swapped-operand bf16-MFMA scores + lazy-packed guarded scan with
// UNSORTED 16-reg list + replace-max insert (short chains). Packed entries
// are unique (score|col) -> replace-exactly-one; sentinels 0xFFFFFFF0+i are
// unique and above any finite packed value. Selection set, guards, and final
// sorted cand output are bit-identical to R12/R14.
// ---------------------------------------------------------------------------
__global__ __launch_bounds__(256) void knn_kernel(
    const unsigned short* __restrict__ H, const float* __restrict__ sq,
    unsigned short* __restrict__ cand)
{
  __shared__ unsigned short Hc[2][64 * 64];   // 2 x 8 KB, swizzled 128B rows
  __shared__ unsigned short Hr[64 * 64];      // 8 KB

  const int bid = blockIdx.x;
  const int b   = bid >> 7;
  const int rt  = (bid >> 1) & 63;
  const int ch  = bid & 1;
  const int r0  = rt * TILE;
  const int c0  = ch * CHCOLS;
  const int tid = threadIdx.x;
  const int w    = tid >> 6;
  const int lane = tid & 63;
  const int lm   = lane & 15;
  const int lk   = lane >> 4;

  const unsigned short* Hb = H + (size_t)b * NN * NC;
  const float* sqg = sq + (size_t)b * NN;

  const int rowS = tid >> 2, subS = tid & 3;
  const int bytS = rowS * 128 + subS * 32;
  const int swzS = (rowS & 7) << 4;

  // ---- prologue: stage Hr (rows) and Hc[0] (col tile 0), XOR-swizzled ----
  {
    const uint4* srcR = (const uint4*)(Hb + (size_t)(r0 + rowS) * NC + subS * 16);
    *(uint4*)((char*)Hr + ((bytS)      ^ swzS)) = srcR[0];
    *(uint4*)((char*)Hr + ((bytS + 16) ^ swzS)) = srcR[1];
    const uint4* srcC = (const uint4*)(Hb + (size_t)(c0 + rowS) * NC + subS * 16);
    *(uint4*)((char*)Hc[0] + ((bytS)      ^ swzS)) = srcC[0];
    *(uint4*)((char*)Hc[0] + ((bytS + 16) ^ swzS)) = srcC[1];
  }
  __syncthreads();

  // ---- B-operand frags: OWN row (persistent) ----
  const int brow = w * 16 + lm;
  const int bswz = (brow & 7) << 4;
  const bf16x8 bf0 = *(const bf16x8*)((const char*)Hr + ((brow * 128 + lk * 16)      ^ bswz));
  const bf16x8 bf1 = *(const bf16x8*)((const char*)Hr + ((brow * 128 + lk * 16 + 64) ^ bswz));

  // unsorted candidate list + tracked max; unique sentinels (> any finite packed)
  unsigned bv[NKL];
  #pragma unroll
  for (int t = 0; t < NKL; ++t) bv[t] = 0xFFFFFFF0u + (unsigned)t;
  unsigned lmax = 0xFFFFFFFFu;
  unsigned rowGuard = 0xFFFFFFFFu;

  for (int t = 0; t < NTILES; ++t) {
    const int cur = t & 1;
    uint4 st0, st1;
    const bool doStage = (t + 1 < NTILES);
    if (doStage) {
      const uint4* src = (const uint4*)(Hb + (size_t)(c0 + (t + 1) * TILE + rowS) * NC + subS * 16);
      st0 = src[0]; st1 = src[1];
    }
    const int n1 = c0 + t * TILE;

    // ---- MFMA: A = col frags (from Hc), B = own-row frags ----
    f32x4 acc[4];
    #pragma unroll
    for (int ct = 0; ct < 4; ++ct) acc[ct] = (f32x4){0.f, 0.f, 0.f, 0.f};
    #pragma unroll
    for (int ct = 0; ct < 4; ++ct) {
      const int arow = ct * 16 + lm;
      const int aswz = (arow & 7) << 4;
      bf16x8 a0 = *(const bf16x8*)((const char*)Hc[cur] + ((arow * 128 + lk * 16)      ^ aswz));
      bf16x8 a1 = *(const bf16x8*)((const char*)Hc[cur] + ((arow * 128 + lk * 16 + 64) ^ aswz));
      acc[ct] = __builtin_amdgcn_mfma_f32_16x16x32_bf16(a0, bf0, acc[ct], 0, 0, 0);
      acc[ct] = __builtin_amdgcn_mfma_f32_16x16x32_bf16(a1, bf1, acc[ct], 0, 0, 0);
    }

    // ---- float scores + explicit-tree min (depth 4) ----
    float dd[16];
    #pragma unroll
    for (int ct = 0; ct < 4; ++ct) {
      const float4 s4 = *(const float4*)&sqg[n1 + ct * 16 + lk * 4];
      dd[ct*4+0] = fmaf(-2.f, acc[ct][0], s4.x);
      dd[ct*4+1] = fmaf(-2.f, acc[ct][1], s4.y);
      dd[ct*4+2] = fmaf(-2.f, acc[ct][2], s4.z);
      dd[ct*4+3] = fmaf(-2.f, acc[ct][3], s4.w);
    }
    float fa0 = fminf(dd[0], dd[1]),  fa1 = fminf(dd[2], dd[3]);
    float fa2 = fminf(dd[4], dd[5]),  fa3 = fminf(dd[6], dd[7]);
    float fa4 = fminf(dd[8], dd[9]),  fa5 = fminf(dd[10], dd[11]);
    float fa6 = fminf(dd[12], dd[13]), fa7 = fminf(dd[14], dd[15]);
    fa0 = fminf(fa0, fa1); fa2 = fminf(fa2, fa3);
    fa4 = fminf(fa4, fa5); fa6 = fminf(fa6, fa7);
    const float fm = fminf(fminf(fa0, fa2), fminf(fa4, fa6));

    // ---- exact lazy skip ----
    unsigned guard = umin32(lmax, rowGuard);
    const unsigned t1 = fmap(fm) & 0xFFFFF800u;
    if (__any(t1 < guard)) {
      // pack all 16: (fmap & ~0x7FF) | chunk-local col
      unsigned pd[16];
      #pragma unroll
      for (int ct = 0; ct < 4; ++ct) {
        const int cbase = (t << 6) + (ct << 4) + (lk << 2);
        pd[ct*4+0] = (fmap(dd[ct*4+0]) & 0xFFFFF800u) | (unsigned)(cbase + 0);
        pd[ct*4+1] = (fmap(dd[ct*4+1]) & 0xFFFFF800u) | (unsigned)(cbase + 1);
        pd[ct*4+2] = (fmap(dd[ct*4+2]) & 0xFFFFF800u) | (unsigned)(cbase + 2);
        pd[ct*4+3] = (fmap(dd[ct*4+3]) & 0xFFFFF800u) | (unsigned)(cbase + 3);
      }
      // tree min over pd
      unsigned pa0 = umin32(pd[0], pd[1]),  pa1 = umin32(pd[2], pd[3]);
      unsigned pa2 = umin32(pd[4], pd[5]),  pa3 = umin32(pd[6], pd[7]);
      unsigned pa4 = umin32(pd[8], pd[9]),  pa5 = umin32(pd[10], pd[11]);
      unsigned pa6 = umin32(pd[12], pd[13]), pa7 = umin32(pd[14], pd[15]);
      pa0 = umin32(pa0, pa1); pa2 = umin32(pa2, pa3);
      pa4 = umin32(pa4, pa5); pa6 = umin32(pa6, pa7);
      unsigned pm = umin32(umin32(pa0, pa2), umin32(pa4, pa6));

      #pragma unroll 1
      for (int rnd = 0; rnd < 16; ++rnd) {
        bool ins = pm < guard;
        if (!__any(ins)) break;
        // replace-max insert: newv==lmax for non-inserting lanes (no-op)
        const unsigned newv = ins ? pm : lmax;
        const unsigned xv   = ins ? pm : 0xFFFFFFFFu;
        #pragma unroll
        for (int i = 0; i < NKL; ++i)
          bv[i] = (bv[i] == lmax) ? newv : bv[i];
        // tree max recompute (depth 4)
        unsigned ma0 = umax32(bv[0], bv[1]),  ma1 = umax32(bv[2], bv[3]);
        unsigned ma2 = umax32(bv[4], bv[5]),  ma3 = umax32(bv[6], bv[7]);
        unsigned ma4 = umax32(bv[8], bv[9]),  ma5 = umax32(bv[10], bv[11]);
        unsigned ma6 = umax32(bv[12], bv[13]), ma7 = umax32(bv[14], bv[15]);
        ma0 = umax32(ma0, ma1); ma2 = umax32(ma2, ma3);
        ma4 = umax32(ma4, ma5); ma6 = umax32(ma6, ma7);
        lmax = umax32(umax32(ma0, ma2), umax32(ma4, ma6));
        // mask extracted entry; recompute pd tree-min
        #pragma unroll
        for (int i = 0; i < 16; ++i) pd[i] = (pd[i] == xv) ? 0xFFFFFFFFu : pd[i];
        pa0 = umin32(pd[0], pd[1]);  pa1 = umin32(pd[2], pd[3]);
        pa2 = umin32(pd[4], pd[5]);  pa3 = umin32(pd[6], pd[7]);
        pa4 = umin32(pd[8], pd[9]);  pa5 = umin32(pd[10], pd[11]);
        pa6 = umin32(pd[12], pd[13]); pa7 = umin32(pd[14], pd[15]);
        pa0 = umin32(pa0, pa1); pa2 = umin32(pa2, pa3);
        pa4 = umin32(pa4, pa5); pa6 = umin32(pa6, pa7);
        pm = umin32(umin32(pa0, pa2), umin32(pa4, pa6));
        // refresh row guard (lanes lm, lm^16, lm^32, lm^48 hold this row)
        unsigned g15 = lmax;
        g15 = umin32(g15, shflx(g15, 16));
        g15 = umin32(g15, shflx(g15, 32));
        rowGuard = g15;
        guard = rowGuard;
      }
    }

    // ---- write staged tile into the OTHER buffer; single barrier ----
    if (doStage) {
      *(uint4*)((char*)Hc[cur ^ 1] + ((bytS)      ^ swzS)) = st0;
      *(uint4*)((char*)Hc[cur ^ 1] + ((bytS + 16) ^ swzS)) = st1;
    }
    __syncthreads();
  }

  // ---- epilogue: dump 4 unsorted lane lists; lane0 exact sorted top-16 ----
  unsigned* mv = (unsigned*)&Hc[0][0];           // 64 rows x 4 x 16 u32 = 16 KB
  const int myrow = w * 16 + lm;
  __syncthreads();
  #pragma unroll
  for (int t = 0; t < NKL; ++t) mv[(myrow * 4 + lk) * NKL + t] = bv[t];
  __syncthreads();
  if (lk == 0) {
    unsigned sel[NKL];
    #pragma unroll
    for (int q = 0; q < NKL; ++q) sel[q] = 0xFFFFFFFFu;
    #pragma unroll 1
    for (int k = 0; k < 4 * NKL; ++k) {
      unsigned v = mv[(myrow * 4) * NKL + k];
      if (v < sel[NKL - 1]) {
        sel[NKL - 1] = v;
        #pragma unroll
        for (int q = NKL - 1; q > 0; --q) {
          if (sel[q] < sel[q - 1]) { unsigned tt = sel[q]; sel[q] = sel[q - 1]; sel[q - 1] = tt; }
        }
      }
    }
    unsigned short* cp = cand + (size_t)(b * NN + r0 + myrow) * NKC + ch * NKL;
    #pragma unroll
    for (int q = 0; q < NKL; ++q)
      cp[q] = (unsigned short)((sel[q] & 0x7FFu) + c0);
  }
}

// ---------------------------------------------------------------------------
// Kernel 3 (R11-R14-proven): exact fp32 rescore, one lane per (row, candidate).
// nn overlays cand: exact 64B/row overlay, block-local RAW.
// ---------------------------------------------------------------------------
__global__ __launch_bounds__(256) void rescore_kernel(
    const float* __restrict__ XT, const float* __restrict__ sq,
    unsigned short* __restrict__ cand, int* __restrict__ nn_idx)
{
  __shared__ float dv[8][NKC];
  __shared__ unsigned short di[8][NKC];
  const int tid  = threadIdx.x;
  const int w    = tid >> 6;
  const int lane = tid & 63;
  const int rowL = w * 2 + (lane >> 5);      // 0..7
  const int q    = lane & 31;
  const int row  = blockIdx.x * 8 + rowL;
  const int b = row >> 12, n = row & (NN - 1);
  const float* xt  = XT + (size_t)b * NN * NC;
  const float* sqg = sq + (size_t)b * NN;

  const int j = (int)cand[(size_t)row * NKC + q];
  const float4* cj = (const float4*)(xt + (size_t)j * NC);
  const float4* cn = (const float4*)(xt + (size_t)n * NC);
  float s = 0.f;
  #pragma unroll
  for (int i = 0; i < 16; ++i) {
    float4 a = cn[i], bb = cj[i];
    s = fmaf(a.x, bb.x, s);
    s = fmaf(a.y, bb.y, s);
    s = fmaf(a.z, bb.z, s);
    s = fmaf(a.w, bb.w, s);
  }
  dv[rowL][q] = fmaf(-2.f, s, sqg[j]);
  di[rowL][q] = (unsigned short)j;
  __syncthreads();

  if (tid < 8) {
    const int row2 = blockIdx.x * 8 + tid;
    float bvv[NK]; int bbi[NK];
    #pragma unroll
    for (int p = 0; p < NK; ++p) { bvv[p] = 3.0e38f; bbi[p] = 0; }
    for (int t = 0; t < NKC; ++t) {
      float v = dv[tid][t];
      if (v < bvv[NK - 1]) {
        bvv[NK - 1] = v; bbi[NK - 1] = (int)di[tid][t];
        #pragma unroll
        for (int p = NK - 1; p > 0; --p) {
          if (bvv[p] < bvv[p - 1]) {
            float tv = bvv[p]; bvv[p] = bvv[p - 1]; bvv[p - 1] = tv;
            int   ti = bbi[p]; bbi[p] = bbi[p - 1]; bbi[p - 1] = ti;
          }
        }
      }
    }
    int* np = nn_idx + (size_t)row2 * NK;
    #pragma unroll
    for (int p = 0; p < NK; ++p) np[p] = bbi[p];
  }
}

// ---------------------------------------------------------------------------
// Kernel 4 (R13/R14-proven): gather interleaved P2|Q2 (one u32/lane), softmax.
// ---------------------------------------------------------------------------
__global__ __launch_bounds__(256) void out_kernel(
    const unsigned short* __restrict__ PQb, const int* __restrict__ nn_idx,
    float* __restrict__ out)
{
  __shared__ float ot[TILE][TILE + 1];
  const int bid = blockIdx.x;
  const int b   = bid >> 6;
  const int n0  = (bid & 63) * TILE;
  const int tid = threadIdx.x;
  const int w = tid >> 6, o = tid & 63;

  for (int pi = 0; pi < 16; ++pi) {
    const int p = w * 16 + pi;
    const int n = n0 + p;
    const unsigned short* pqn = PQb + (size_t)(b * NN + n) * 192;
    const float p1b  = bf2f(pqn[o]);
    const int* idxp  = nn_idx + (size_t)(b * NN + n) * NK;
    float p2[NK], q2[NK];
    #pragma unroll
    for (int t = 0; t < NK; ++t) {
      int jn = idxp[t];
      unsigned u = *(const unsigned*)(PQb + (size_t)(b * NN + jn) * 192 + 64 + 2 * o);
      p2[t] = bf2f((unsigned short)(u & 0xFFFFu));
      q2[t] = bf2f((unsigned short)(u >> 16));
    }
    float m = q2[0];
    #pragma unroll
    for (int t = 1; t < NK; ++t) m = fmaxf(m, q2[t]);
    float s = 0.f, num = 0.f;
    #pragma unroll
    for (int t = 0; t < NK; ++t) {
      float e = __expf(q2[t] - m);
      s += e;
      num = fmaf(e, p1b + p2[t], num);
    }
    ot[p][o] = num / s;
  }
  __syncthreads();

  const int oo = tid >> 2, qq = tid & 3;
  float* og = out + (size_t)(b * NO + oo) * NN + n0 + qq * 16;
  #pragma unroll
  for (int i = 0; i < 4; ++i) {
    float4 v;
    v.x = ot[qq * 16 + i * 4 + 0][oo];
    v.y = ot[qq * 16 + i * 4 + 1][oo];
    v.z = ot[qq * 16 + i * 4 + 2][oo];
    v.w = ot[qq * 16 + i * 4 + 3][oo];
    *(float4*)&og[i * 4] = v;
  }
}

// ---------------------------------------------------------------------------
extern "C" void kernel_launch(void* const* d_in, const int* in_sizes, int n_in,
                              void* d_out, int out_size, void* d_ws, size_t ws_size,
                              hipStream_t stream)
{
  const float* x  = (const float*)d_in[0];
  const float* We = (const float*)d_in[1];
  const float* be = (const float*)d_in[2];
  const float* Wa = (const float*)d_in[3];
  float* out = (float*)d_out;

  // workspace: 26.8 MB (< proven 33.69 MB envelope)
  char* ws = (char*)d_ws;
  size_t off = 0;
  float* sq = (float*)(ws + off);                    off += (size_t)NB * NN * 4;        // 128 KB
  unsigned short* PQb = (unsigned short*)(ws + off); off += (size_t)NB * NN * 192 * 2;  // 12.6 MB
  float* XT = (float*)(ws + off);                    off += (size_t)NB * NN * NC * 4;   // 8 MB
  unsigned short* H = (unsigned short*)(ws + off);   off += (size_t)NB * NN * NC * 2;   // 4 MB
  unsigned short* cand = (unsigned short*)(ws + off);                                   // 2 MB
  int* nn = (int*)cand;   // exact per-row 64B overlay; written after reads (block-local)

  dim3 blk(256);
  proj_kernel<<<dim3(NB * (NN / TILE)), blk, 0, stream>>>(x, We, be, Wa, PQb, sq, XT, H);
  knn_kernel<<<dim3(NB * (NN / TILE) * NCHUNK), blk, 0, stream>>>(H, sq, cand);
  rescore_kernel<<<dim3(NB * NN / 8), blk, 0, stream>>>(XT, sq, cand, nn);
  out_kernel<<<dim3(NB * (NN / TILE)), blk, 0, stream>>>(PQb, nn, out);
}

// Round 16
// 287.028 us; speedup vs baseline: 1.1344x; 1.1344x over previous
//
#include <hip/hip_runtime.h>
#include <hip/hip_bf16.h>
#include <stdint.h>

#define NB 8
#define NC 64
#define NN 4096
#define NK 16
#define NO 64
#define TILE 64
#define NCHUNK 2
#define CHCOLS (NN / NCHUNK)     // 2048
#define NTILES (CHCOLS / TILE)   // 32
#define NKL 16                   // per-lane guarded candidate list
#define NKC 32                   // candidates per row for rescore (2 x 16)

typedef __attribute__((ext_vector_type(8))) short bf16x8;
typedef __attribute__((ext_vector_type(4))) float f32x4;

__device__ __forceinline__ unsigned umin32(unsigned a, unsigned b) { return a < b ? a : b; }
__device__ __forceinline__ unsigned shflx(unsigned v, int m) {
  return (unsigned)__shfl_xor((int)v, m);
}
// order-preserving fp32 -> uint map
__device__ __forceinline__ unsigned fmap(float x) {
  unsigned u = __float_as_uint(x);
  return u ^ ((unsigned)((int)u >> 31) | 0x80000000u);
}
__device__ __forceinline__ float bf2f(unsigned short h) {
  return __bfloat162float(*reinterpret_cast<__hip_bfloat16*>(&h));
}
__device__ __forceinline__ unsigned short f2bfu(float v) {
  __hip_bfloat16 hh = __float2bfloat16(v);
  return *reinterpret_cast<unsigned short*>(&hh);
}

// ---------------------------------------------------------------------------
// Kernel 1 (R13/R14-proven): projections + norms + fp32 XT + bf16 H.
// PQb[b][n] (192 u16): [0..63] = P1+bias, [64+2o] = P2[o], [64+2o+1] = Q2[o].
// ---------------------------------------------------------------------------
__global__ __launch_bounds__(256) void proj_kernel(
    const float* __restrict__ x, const float* __restrict__ We,
    const float* __restrict__ be, const float* __restrict__ Wa,
    unsigned short* __restrict__ PQb, float* __restrict__ sq,
    float* __restrict__ XT, unsigned short* __restrict__ H)
{
  __shared__ float xs[NC][TILE];
  __shared__ float wt[NC][192];
  const int bid = blockIdx.x;
  const int b   = bid >> 6;
  const int n0  = (bid & 63) * TILE;
  const int tid = threadIdx.x;

  const float4* xg4 = (const float4*)x;
  float4* xs4 = (float4*)xs;
  for (int i = tid; i < NC * TILE / 4; i += 256) {
    int c = i >> 4, p4 = i & 15;
    xs4[c * 16 + p4] = xg4[(b * NC + c) * (NN / 4) + (n0 >> 2) + p4];
  }
  for (int i = tid; i < 64 * NC; i += 256) {
    int o = i >> 6, c = i & 63;
    float w1 = We[o * 128 + c], w2 = We[o * 128 + 64 + c];
    wt[c][o]        = w1 - w2;
    wt[c][64 + o]   = w2;
    wt[c][128 + o]  = Wa[o * 128 + 64 + c];
  }
  __syncthreads();

  {
    const int p = tid & 63, cg = tid >> 6;
    union { float4 v4[4]; float f[16]; } vv;
    #pragma unroll
    for (int g = 0; g < 4; ++g) {
      vv.v4[g].x = xs[cg * 16 + g * 4 + 0][p];
      vv.v4[g].y = xs[cg * 16 + g * 4 + 1][p];
      vv.v4[g].z = xs[cg * 16 + g * 4 + 2][p];
      vv.v4[g].w = xs[cg * 16 + g * 4 + 3][p];
    }
    float4* Xp = (float4*)(XT + ((size_t)(b * NN + n0 + p) * NC + cg * 16));
    Xp[0] = vv.v4[0]; Xp[1] = vv.v4[1]; Xp[2] = vv.v4[2]; Xp[3] = vv.v4[3];
    union { unsigned short h[16]; uint4 u[2]; } hs;
    #pragma unroll
    for (int i = 0; i < 16; ++i) hs.h[i] = f2bfu(vv.f[i]);
    uint4* Hp = (uint4*)(H + ((size_t)(b * NN + n0 + p) * NC + cg * 16));
    Hp[0] = hs.u[0]; Hp[1] = hs.u[1];
  }

  if (tid >= 192) {
    int p = tid - 192;
    float s = 0.f;
    #pragma unroll
    for (int c = 0; c < NC; ++c) { float v = xs[c][p]; s = fmaf(v, v, s); }
    sq[b * NN + n0 + p] = s;
  } else {
    const int r = tid;
    float wreg[NC];
    #pragma unroll
    for (int c = 0; c < NC; ++c) wreg[c] = wt[c][r];
    const float bias = (r < 64) ? be[r] : 0.f;
    const int ridx = (r < 64) ? r
                   : (r < 128) ? (64 + 2 * (r - 64))
                               : (64 + 2 * (r - 128) + 1);
    for (int p = 0; p < TILE; p += 4) {
      float a0 = bias, a1 = bias, a2 = bias, a3 = bias;
      #pragma unroll
      for (int c = 0; c < NC; ++c) {
        float4 xv = *(const float4*)&xs[c][p];
        a0 = fmaf(wreg[c], xv.x, a0);
        a1 = fmaf(wreg[c], xv.y, a1);
        a2 = fmaf(wreg[c], xv.z, a2);
        a3 = fmaf(wreg[c], xv.w, a3);
      }
      size_t base = (size_t)(b * NN + n0 + p) * 192 + ridx;
      PQb[base]           = f2bfu(a0);
      PQb[base + 192]     = f2bfu(a1);
      PQb[base + 2*192]   = f2bfu(a2);
      PQb[base + 3*192]   = f2bfu(a3);
    }
  }
}

// ---------------------------------------------------------------------------
// Kernel 2 (R14 scan verbatim; Hr removed from LDS -> 16384 B = 4 blocks/CU,
// 16 waves/CU, grid 1024 = exactly 4/CU zero-tail). B-frags read once from
// global H (L2-hot; addressing proven in R13). Selection bit-identical.
// ---------------------------------------------------------------------------
__global__ __launch_bounds__(256) void knn_kernel(
    const unsigned short* __restrict__ H, const float* __restrict__ sq,
    unsigned short* __restrict__ cand)
{
  __shared__ unsigned short Hc[2][64 * 64];   // 16384 B total, swizzled 128B rows

  const int bid = blockIdx.x;
  const int b   = bid >> 7;
  const int rt  = (bid >> 1) & 63;
  const int ch  = bid & 1;
  const int r0  = rt * TILE;
  const int c0  = ch * CHCOLS;
  const int tid = threadIdx.x;
  const int w    = tid >> 6;
  const int lane = tid & 63;
  const int lm   = lane & 15;
  const int lk   = lane >> 4;

  const unsigned short* Hb = H + (size_t)b * NN * NC;
  const float* sqg = sq + (size_t)b * NN;

  const int rowS = tid >> 2, subS = tid & 3;
  const int bytS = rowS * 128 + subS * 32;
  const int swzS = (rowS & 7) << 4;

  // ---- prologue: stage Hc[0] (col tile 0), XOR-swizzled ----
  {
    const uint4* srcC = (const uint4*)(Hb + (size_t)(c0 + rowS) * NC + subS * 16);
    *(uint4*)((char*)Hc[0] + ((bytS)      ^ swzS)) = srcC[0];
    *(uint4*)((char*)Hc[0] + ((bytS + 16) ^ swzS)) = srcC[1];
  }

  // ---- B-operand frags: OWN row, straight from global H (once, persistent) ----
  const int brow = w * 16 + lm;
  const unsigned short* hrow = Hb + (size_t)(r0 + brow) * NC;
  const bf16x8 bf0 = *(const bf16x8*)(hrow + lk * 8);        // bytes lk*16
  const bf16x8 bf1 = *(const bf16x8*)(hrow + lk * 8 + 32);   // bytes lk*16+64
  __syncthreads();

  unsigned bv[NKL];
  #pragma unroll
  for (int t = 0; t < NKL; ++t) bv[t] = 0xFFFFFFFFu;
  unsigned rowGuard = 0xFFFFFFFFu;

  for (int t = 0; t < NTILES; ++t) {
    const int cur = t & 1;
    uint4 st0, st1;
    const bool doStage = (t + 1 < NTILES);
    if (doStage) {
      const uint4* src = (const uint4*)(Hb + (size_t)(c0 + (t + 1) * TILE + rowS) * NC + subS * 16);
      st0 = src[0]; st1 = src[1];
    }
    const int n1 = c0 + t * TILE;

    // ---- MFMA: A = col frags (from Hc), B = own-row frags ----
    f32x4 acc[4];
    #pragma unroll
    for (int ct = 0; ct < 4; ++ct) acc[ct] = (f32x4){0.f, 0.f, 0.f, 0.f};
    #pragma unroll
    for (int ct = 0; ct < 4; ++ct) {
      const int arow = ct * 16 + lm;
      const int aswz = (arow & 7) << 4;
      bf16x8 a0 = *(const bf16x8*)((const char*)Hc[cur] + ((arow * 128 + lk * 16)      ^ aswz));
      bf16x8 a1 = *(const bf16x8*)((const char*)Hc[cur] + ((arow * 128 + lk * 16 + 64) ^ aswz));
      acc[ct] = __builtin_amdgcn_mfma_f32_16x16x32_bf16(a0, bf0, acc[ct], 0, 0, 0);
      acc[ct] = __builtin_amdgcn_mfma_f32_16x16x32_bf16(a1, bf1, acc[ct], 0, 0, 0);
    }

    // ---- float scores (free from accumulators) + float min-tree ----
    float dd[16];
    #pragma unroll
    for (int ct = 0; ct < 4; ++ct) {
      const float4 s4 = *(const float4*)&sqg[n1 + ct * 16 + lk * 4];
      dd[ct*4+0] = fmaf(-2.f, acc[ct][0], s4.x);
      dd[ct*4+1] = fmaf(-2.f, acc[ct][1], s4.y);
      dd[ct*4+2] = fmaf(-2.f, acc[ct][2], s4.z);
      dd[ct*4+3] = fmaf(-2.f, acc[ct][3], s4.w);
    }
    float fm = dd[0];
    #pragma unroll
    for (int i = 1; i < 16; ++i) fm = fminf(fm, dd[i]);

    // ---- exact lazy skip ----
    unsigned guard = umin32(bv[NKL - 1], rowGuard);
    const unsigned t1 = fmap(fm) & 0xFFFFF800u;
    if (__any(t1 < guard)) {
      // pack all 16: (fmap & ~0x7FF) | chunk-local col
      unsigned pd[16];
      #pragma unroll
      for (int ct = 0; ct < 4; ++ct) {
        const int cbase = (t << 6) + (ct << 4) + (lk << 2);
        pd[ct*4+0] = (fmap(dd[ct*4+0]) & 0xFFFFF800u) | (unsigned)(cbase + 0);
        pd[ct*4+1] = (fmap(dd[ct*4+1]) & 0xFFFFF800u) | (unsigned)(cbase + 1);
        pd[ct*4+2] = (fmap(dd[ct*4+2]) & 0xFFFFF800u) | (unsigned)(cbase + 2);
        pd[ct*4+3] = (fmap(dd[ct*4+3]) & 0xFFFFF800u) | (unsigned)(cbase + 3);
      }
      unsigned pm = pd[0];
      #pragma unroll
      for (int i = 1; i < 16; ++i) pm = umin32(pm, pd[i]);

      #pragma unroll 1
      for (int rnd = 0; rnd < 16; ++rnd) {
        bool ins = pm < guard;
        if (!__any(ins)) break;
        unsigned x = ins ? pm : 0xFFFFFFFFu;
        const unsigned xv = x;
        #pragma unroll
        for (int i = 0; i < NKL; ++i) {
          unsigned lo = umin32(bv[i], x);
          x = bv[i] < x ? x : bv[i];   // max
          bv[i] = lo;
        }
        #pragma unroll
        for (int i = 0; i < 16; ++i) pd[i] = (pd[i] == xv) ? 0xFFFFFFFFu : pd[i];
        pm = pd[0];
        #pragma unroll
        for (int i = 1; i < 16; ++i) pm = umin32(pm, pd[i]);
        // refresh row guard (lanes lm, lm^16, lm^32, lm^48 hold this row)
        unsigned g15 = bv[NKL - 1];
        g15 = umin32(g15, shflx(g15, 16));
        g15 = umin32(g15, shflx(g15, 32));
        rowGuard = g15;
        guard = rowGuard;
      }
    }

    // ---- write staged tile into the OTHER buffer; single barrier ----
    if (doStage) {
      *(uint4*)((char*)Hc[cur ^ 1] + ((bytS)      ^ swzS)) = st0;
      *(uint4*)((char*)Hc[cur ^ 1] + ((bytS + 16) ^ swzS)) = st1;
    }
    __syncthreads();
  }

  // ---- epilogue: merge 4 lane lists -> exact packed-top-16 per row ----
  unsigned* mv = (unsigned*)&Hc[0][0];           // 64 rows x 4 x 16 u32 = 16384 B
  const int myrow = w * 16 + lm;
  __syncthreads();
  #pragma unroll
  for (int t = 0; t < NKL; ++t) mv[(myrow * 4 + lk) * NKL + t] = bv[t];
  __syncthreads();
  if (lk == 0) {
    for (int s2 = 1; s2 < 4; ++s2) {
      for (int t = 0; t < NKL; ++t) {
        unsigned v = mv[(myrow * 4 + s2) * NKL + t];
        if (v >= bv[NKL - 1]) break;   // lane lists sorted ascending
        unsigned x = v;
        #pragma unroll
        for (int q = 0; q < NKL; ++q) {
          unsigned lo = umin32(bv[q], x);
          x = bv[q] < x ? x : bv[q];
          bv[q] = lo;
        }
      }
    }
    unsigned short* cp = cand + (size_t)(b * NN + r0 + myrow) * NKC + ch * NKL;
    #pragma unroll
    for (int t = 0; t < NKL; ++t)
      cp[t] = (unsigned short)((bv[t] & 0x7FFu) + c0);
  }
}

// ---------------------------------------------------------------------------
// Kernel 3 (R11-R14-proven): exact fp32 rescore, one lane per (row, candidate).
// nn overlays cand: exact 64B/row overlay, block-local RAW.
// ---------------------------------------------------------------------------
__global__ __launch_bounds__(256) void rescore_kernel(
    const float* __restrict__ XT, const float* __restrict__ sq,
    unsigned short* __restrict__ cand, int* __restrict__ nn_idx)
{
  __shared__ float dv[8][NKC];
  __shared__ unsigned short di[8][NKC];
  const int tid  = threadIdx.x;
  const int w    = tid >> 6;
  const int lane = tid & 63;
  const int rowL = w * 2 + (lane >> 5);      // 0..7
  const int q    = lane & 31;
  const int row  = blockIdx.x * 8 + rowL;
  const int b = row >> 12, n = row & (NN - 1);
  const float* xt  = XT + (size_t)b * NN * NC;
  const float* sqg = sq + (size_t)b * NN;

  const int j = (int)cand[(size_t)row * NKC + q];
  const float4* cj = (const float4*)(xt + (size_t)j * NC);
  const float4* cn = (const float4*)(xt + (size_t)n * NC);
  float s = 0.f;
  #pragma unroll
  for (int i = 0; i < 16; ++i) {
    float4 a = cn[i], bb = cj[i];
    s = fmaf(a.x, bb.x, s);
    s = fmaf(a.y, bb.y, s);
    s = fmaf(a.z, bb.z, s);
    s = fmaf(a.w, bb.w, s);
  }
  dv[rowL][q] = fmaf(-2.f, s, sqg[j]);
  di[rowL][q] = (unsigned short)j;
  __syncthreads();

  if (tid < 8) {
    const int row2 = blockIdx.x * 8 + tid;
    float bvv[NK]; int bbi[NK];
    #pragma unroll
    for (int p = 0; p < NK; ++p) { bvv[p] = 3.0e38f; bbi[p] = 0; }
    for (int t = 0; t < NKC; ++t) {
      float v = dv[tid][t];
      if (v < bvv[NK - 1]) {
        bvv[NK - 1] = v; bbi[NK - 1] = (int)di[tid][t];
        #pragma unroll
        for (int p = NK - 1; p > 0; --p) {
          if (bvv[p] < bvv[p - 1]) {
            float tv = bvv[p]; bvv[p] = bvv[p - 1]; bvv[p - 1] = tv;
            int   ti = bbi[p]; bbi[p] = bbi[p - 1]; bbi[p - 1] = ti;
          }
        }
      }
    }
    int* np = nn_idx + (size_t)row2 * NK;
    #pragma unroll
    for (int p = 0; p < NK; ++p) np[p] = bbi[p];
  }
}

// ---------------------------------------------------------------------------
// Kernel 4 (R13/R14-proven): gather interleaved P2|Q2 (one u32/lane), softmax.
// ---------------------------------------------------------------------------
__global__ __launch_bounds__(256) void out_kernel(
    const unsigned short* __restrict__ PQb, const int* __restrict__ nn_idx,
    float* __restrict__ out)
{
  __shared__ float ot[TILE][TILE + 1];
  const int bid = blockIdx.x;
  const int b   = bid >> 6;
  const int n0  = (bid & 63) * TILE;
  const int tid = threadIdx.x;
  const int w = tid >> 6, o = tid & 63;

  for (int pi = 0; pi < 16; ++pi) {
    const int p = w * 16 + pi;
    const int n = n0 + p;
    const unsigned short* pqn = PQb + (size_t)(b * NN + n) * 192;
    const float p1b  = bf2f(pqn[o]);
    const int* idxp  = nn_idx + (size_t)(b * NN + n) * NK;
    float p2[NK], q2[NK];
    #pragma unroll
    for (int t = 0; t < NK; ++t) {
      int jn = idxp[t];
      unsigned u = *(const unsigned*)(PQb + (size_t)(b * NN + jn) * 192 + 64 + 2 * o);
      p2[t] = bf2f((unsigned short)(u & 0xFFFFu));
      q2[t] = bf2f((unsigned short)(u >> 16));
    }
    float m = q2[0];
    #pragma unroll
    for (int t = 1; t < NK; ++t) m = fmaxf(m, q2[t]);
    float s = 0.f, num = 0.f;
    #pragma unroll
    for (int t = 0; t < NK; ++t) {
      float e = __expf(q2[t] - m);
      s += e;
      num = fmaf(e, p1b + p2[t], num);
    }
    ot[p][o] = num / s;
  }
  __syncthreads();

  const int oo = tid >> 2, qq = tid & 3;
  float* og = out + (size_t)(b * NO + oo) * NN + n0 + qq * 16;
  #pragma unroll
  for (int i = 0; i < 4; ++i) {
    float4 v;
    v.x = ot[qq * 16 + i * 4 + 0][oo];
    v.y = ot[qq * 16 + i * 4 + 1][oo];
    v.z = ot[qq * 16 + i * 4 + 2][oo];
    v.w = ot[qq * 16 + i * 4 + 3][oo];
    *(float4*)&og[i * 4] = v;
  }
}

// ---------------------------------------------------------------------------
extern "C" void kernel_launch(void* const* d_in, const int* in_sizes, int n_in,
                              void* d_out, int out_size, void* d_ws, size_t ws_size,
                              hipStream_t stream)
{
  const float* x  = (const float*)d_in[0];
  const float* We = (const float*)d_in[1];
  const float* be = (const float*)d_in[2];
  const float* Wa = (const float*)d_in[3];
  float* out = (float*)d_out;

  // workspace: 26.8 MB (< proven 33.69 MB envelope)
  char* ws = (char*)d_ws;
  size_t off = 0;
  float* sq = (float*)(ws + off);                    off += (size_t)NB * NN * 4;        // 128 KB
  unsigned short* PQb = (unsigned short*)(ws + off); off += (size_t)NB * NN * 192 * 2;  // 12.6 MB
  float* XT = (float*)(ws + off);                    off += (size_t)NB * NN * NC * 4;   // 8 MB
  unsigned short* H = (unsigned short*)(ws + off);   off += (size_t)NB * NN * NC * 2;   // 4 MB
  unsigned short* cand = (unsigned short*)(ws + off);                                   // 2 MB
  int* nn = (int*)cand;   // exact per-row 64B overlay; written after reads (block-local)

  dim3 blk(256);
  proj_kernel<<<dim3(NB * (NN / TILE)), blk, 0, stream>>>(x, We, be, Wa, PQb, sq, XT, H);
  knn_kernel<<<dim3(NB * (NN / TILE) * NCHUNK), blk, 0, stream>>>(H, sq, cand);
  rescore_kernel<<<dim3(NB * NN / 8), blk, 0, stream>>>(XT, sq, cand, nn);
  out_kernel<<<dim3(NB * (NN / TILE)), blk, 0, stream>>>(PQb, nn, out);
}

// Round 17
// 281.269 us; speedup vs baseline: 1.1576x; 1.0205x over previous
//
#include <hip/hip_runtime.h>
#include <hip/hip_bf16.h>
#include <stdint.h>

#define NB 8
#define NC 64
#define NN 4096
#define NK 16
#define NO 64
#define TILE 64
#define NCHUNK 2
#define CHCOLS (NN / NCHUNK)     // 2048
#define NTILES (CHCOLS / TILE)   // 32
#define NKL 16                   // per-lane guarded candidate list
#define NKC 32                   // candidates per row for rescore (2 x 16)

typedef __attribute__((ext_vector_type(8))) short bf16x8;
typedef __attribute__((ext_vector_type(4))) float f32x4;

__device__ __forceinline__ unsigned umin32(unsigned a, unsigned b) { return a < b ? a : b; }
__device__ __forceinline__ unsigned shflx(unsigned v, int m) {
  return (unsigned)__shfl_xor((int)v, m);
}
// order-preserving fp32 -> uint map
__device__ __forceinline__ unsigned fmap(float x) {
  unsigned u = __float_as_uint(x);
  return u ^ ((unsigned)((int)u >> 31) | 0x80000000u);
}
__device__ __forceinline__ float bf2f(unsigned short h) {
  return __bfloat162float(*reinterpret_cast<__hip_bfloat16*>(&h));
}
__device__ __forceinline__ unsigned short f2bfu(float v) {
  __hip_bfloat16 hh = __float2bfloat16(v);
  return *reinterpret_cast<unsigned short*>(&hh);
}

// ---------------------------------------------------------------------------
// Kernel 1 (R13/R14-proven): projections + norms + fp32 XT + bf16 H.
// PQb[b][n] (192 u16): [0..63] = P1+bias, [64+2o] = P2[o], [64+2o+1] = Q2[o].
// ---------------------------------------------------------------------------
__global__ __launch_bounds__(256) void proj_kernel(
    const float* __restrict__ x, const float* __restrict__ We,
    const float* __restrict__ be, const float* __restrict__ Wa,
    unsigned short* __restrict__ PQb, float* __restrict__ sq,
    float* __restrict__ XT, unsigned short* __restrict__ H)
{
  __shared__ float xs[NC][TILE];
  __shared__ float wt[NC][192];
  const int bid = blockIdx.x;
  const int b   = bid >> 6;
  const int n0  = (bid & 63) * TILE;
  const int tid = threadIdx.x;

  const float4* xg4 = (const float4*)x;
  float4* xs4 = (float4*)xs;
  for (int i = tid; i < NC * TILE / 4; i += 256) {
    int c = i >> 4, p4 = i & 15;
    xs4[c * 16 + p4] = xg4[(b * NC + c) * (NN / 4) + (n0 >> 2) + p4];
  }
  for (int i = tid; i < 64 * NC; i += 256) {
    int o = i >> 6, c = i & 63;
    float w1 = We[o * 128 + c], w2 = We[o * 128 + 64 + c];
    wt[c][o]        = w1 - w2;
    wt[c][64 + o]   = w2;
    wt[c][128 + o]  = Wa[o * 128 + 64 + c];
  }
  __syncthreads();

  {
    const int p = tid & 63, cg = tid >> 6;
    union { float4 v4[4]; float f[16]; } vv;
    #pragma unroll
    for (int g = 0; g < 4; ++g) {
      vv.v4[g].x = xs[cg * 16 + g * 4 + 0][p];
      vv.v4[g].y = xs[cg * 16 + g * 4 + 1][p];
      vv.v4[g].z = xs[cg * 16 + g * 4 + 2][p];
      vv.v4[g].w = xs[cg * 16 + g * 4 + 3][p];
    }
    float4* Xp = (float4*)(XT + ((size_t)(b * NN + n0 + p) * NC + cg * 16));
    Xp[0] = vv.v4[0]; Xp[1] = vv.v4[1]; Xp[2] = vv.v4[2]; Xp[3] = vv.v4[3];
    union { unsigned short h[16]; uint4 u[2]; } hs;
    #pragma unroll
    for (int i = 0; i < 16; ++i) hs.h[i] = f2bfu(vv.f[i]);
    uint4* Hp = (uint4*)(H + ((size_t)(b * NN + n0 + p) * NC + cg * 16));
    Hp[0] = hs.u[0]; Hp[1] = hs.u[1];
  }

  if (tid >= 192) {
    int p = tid - 192;
    float s = 0.f;
    #pragma unroll
    for (int c = 0; c < NC; ++c) { float v = xs[c][p]; s = fmaf(v, v, s); }
    sq[b * NN + n0 + p] = s;
  } else {
    const int r = tid;
    float wreg[NC];
    #pragma unroll
    for (int c = 0; c < NC; ++c) wreg[c] = wt[c][r];
    const float bias = (r < 64) ? be[r] : 0.f;
    const int ridx = (r < 64) ? r
                   : (r < 128) ? (64 + 2 * (r - 64))
                               : (64 + 2 * (r - 128) + 1);
    for (int p = 0; p < TILE; p += 4) {
      float a0 = bias, a1 = bias, a2 = bias, a3 = bias;
      #pragma unroll
      for (int c = 0; c < NC; ++c) {
        float4 xv = *(const float4*)&xs[c][p];
        a0 = fmaf(wreg[c], xv.x, a0);
        a1 = fmaf(wreg[c], xv.y, a1);
        a2 = fmaf(wreg[c], xv.z, a2);
        a3 = fmaf(wreg[c], xv.w, a3);
      }
      size_t base = (size_t)(b * NN + n0 + p) * 192 + ridx;
      PQb[base]           = f2bfu(a0);
      PQb[base + 192]     = f2bfu(a1);
      PQb[base + 2*192]   = f2bfu(a2);
      PQb[base + 3*192]   = f2bfu(a3);
    }
  }
}

// ---------------------------------------------------------------------------
// Kernel 2 (R16 structure; rowGuard refresh HOISTED out of the round loop:
// rounds use stale rowGuard + live own bv[15] -- selection-safe superset,
// epilogue exact merge => cand bit-identical). 16 KB LDS, Hr from global.
// ---------------------------------------------------------------------------
__global__ __launch_bounds__(256) void knn_kernel(
    const unsigned short* __restrict__ H, const float* __restrict__ sq,
    unsigned short* __restrict__ cand)
{
  __shared__ unsigned short Hc[2][64 * 64];   // 16384 B total, swizzled 128B rows

  const int bid = blockIdx.x;
  const int b   = bid >> 7;
  const int rt  = (bid >> 1) & 63;
  const int ch  = bid & 1;
  const int r0  = rt * TILE;
  const int c0  = ch * CHCOLS;
  const int tid = threadIdx.x;
  const int w    = tid >> 6;
  const int lane = tid & 63;
  const int lm   = lane & 15;
  const int lk   = lane >> 4;

  const unsigned short* Hb = H + (size_t)b * NN * NC;
  const float* sqg = sq + (size_t)b * NN;

  const int rowS = tid >> 2, subS = tid & 3;
  const int bytS = rowS * 128 + subS * 32;
  const int swzS = (rowS & 7) << 4;

  // ---- prologue: stage Hc[0] (col tile 0), XOR-swizzled ----
  {
    const uint4* srcC = (const uint4*)(Hb + (size_t)(c0 + rowS) * NC + subS * 16);
    *(uint4*)((char*)Hc[0] + ((bytS)      ^ swzS)) = srcC[0];
    *(uint4*)((char*)Hc[0] + ((bytS + 16) ^ swzS)) = srcC[1];
  }

  // ---- B-operand frags: OWN row, straight from global H (once, persistent) ----
  const int brow = w * 16 + lm;
  const unsigned short* hrow = Hb + (size_t)(r0 + brow) * NC;
  const bf16x8 bf0 = *(const bf16x8*)(hrow + lk * 8);
  const bf16x8 bf1 = *(const bf16x8*)(hrow + lk * 8 + 32);
  __syncthreads();

  unsigned bv[NKL];
  #pragma unroll
  for (int t = 0; t < NKL; ++t) bv[t] = 0xFFFFFFFFu;
  unsigned rowGuard = 0xFFFFFFFFu;

  for (int t = 0; t < NTILES; ++t) {
    const int cur = t & 1;
    uint4 st0, st1;
    const bool doStage = (t + 1 < NTILES);
    if (doStage) {
      const uint4* src = (const uint4*)(Hb + (size_t)(c0 + (t + 1) * TILE + rowS) * NC + subS * 16);
      st0 = src[0]; st1 = src[1];
    }
    const int n1 = c0 + t * TILE;

    // ---- MFMA: A = col frags (from Hc), B = own-row frags ----
    f32x4 acc[4];
    #pragma unroll
    for (int ct = 0; ct < 4; ++ct) acc[ct] = (f32x4){0.f, 0.f, 0.f, 0.f};
    #pragma unroll
    for (int ct = 0; ct < 4; ++ct) {
      const int arow = ct * 16 + lm;
      const int aswz = (arow & 7) << 4;
      bf16x8 a0 = *(const bf16x8*)((const char*)Hc[cur] + ((arow * 128 + lk * 16)      ^ aswz));
      bf16x8 a1 = *(const bf16x8*)((const char*)Hc[cur] + ((arow * 128 + lk * 16 + 64) ^ aswz));
      acc[ct] = __builtin_amdgcn_mfma_f32_16x16x32_bf16(a0, bf0, acc[ct], 0, 0, 0);
      acc[ct] = __builtin_amdgcn_mfma_f32_16x16x32_bf16(a1, bf1, acc[ct], 0, 0, 0);
    }

    // ---- float scores (free from accumulators) + float min-tree ----
    float dd[16];
    #pragma unroll
    for (int ct = 0; ct < 4; ++ct) {
      const float4 s4 = *(const float4*)&sqg[n1 + ct * 16 + lk * 4];
      dd[ct*4+0] = fmaf(-2.f, acc[ct][0], s4.x);
      dd[ct*4+1] = fmaf(-2.f, acc[ct][1], s4.y);
      dd[ct*4+2] = fmaf(-2.f, acc[ct][2], s4.z);
      dd[ct*4+3] = fmaf(-2.f, acc[ct][3], s4.w);
    }
    float fm = dd[0];
    #pragma unroll
    for (int i = 1; i < 16; ++i) fm = fminf(fm, dd[i]);

    // ---- exact lazy skip ----
    unsigned guard = umin32(bv[NKL - 1], rowGuard);
    const unsigned t1 = fmap(fm) & 0xFFFFF800u;
    if (__any(t1 < guard)) {
      // pack all 16: (fmap & ~0x7FF) | chunk-local col
      unsigned pd[16];
      #pragma unroll
      for (int ct = 0; ct < 4; ++ct) {
        const int cbase = (t << 6) + (ct << 4) + (lk << 2);
        pd[ct*4+0] = (fmap(dd[ct*4+0]) & 0xFFFFF800u) | (unsigned)(cbase + 0);
        pd[ct*4+1] = (fmap(dd[ct*4+1]) & 0xFFFFF800u) | (unsigned)(cbase + 1);
        pd[ct*4+2] = (fmap(dd[ct*4+2]) & 0xFFFFF800u) | (unsigned)(cbase + 2);
        pd[ct*4+3] = (fmap(dd[ct*4+3]) & 0xFFFFF800u) | (unsigned)(cbase + 3);
      }
      unsigned pm = pd[0];
      #pragma unroll
      for (int i = 1; i < 16; ++i) pm = umin32(pm, pd[i]);

      #pragma unroll 1
      for (int rnd = 0; rnd < 16; ++rnd) {
        bool ins = pm < guard;
        if (!__any(ins)) break;
        unsigned x = ins ? pm : 0xFFFFFFFFu;
        const unsigned xv = x;
        #pragma unroll
        for (int i = 0; i < NKL; ++i) {
          unsigned lo = umin32(bv[i], x);
          x = bv[i] < x ? x : bv[i];   // max
          bv[i] = lo;
        }
        #pragma unroll
        for (int i = 0; i < 16; ++i) pd[i] = (pd[i] == xv) ? 0xFFFFFFFFu : pd[i];
        pm = pd[0];
        #pragma unroll
        for (int i = 1; i < 16; ++i) pm = umin32(pm, pd[i]);
        // guard: live own 16th + STALE rowGuard (no shfl in the loop)
        guard = umin32(bv[NKL - 1], rowGuard);
      }
      // refresh row guard ONCE per inserting tile (2 shfl, off the round path)
      unsigned g15 = bv[NKL - 1];
      g15 = umin32(g15, shflx(g15, 16));
      g15 = umin32(g15, shflx(g15, 32));
      rowGuard = g15;
    }

    // ---- write staged tile into the OTHER buffer; single barrier ----
    if (doStage) {
      *(uint4*)((char*)Hc[cur ^ 1] + ((bytS)      ^ swzS)) = st0;
      *(uint4*)((char*)Hc[cur ^ 1] + ((bytS + 16) ^ swzS)) = st1;
    }
    __syncthreads();
  }

  // ---- epilogue: merge 4 lane lists -> exact packed-top-16 per row ----
  unsigned* mv = (unsigned*)&Hc[0][0];           // 64 rows x 4 x 16 u32 = 16384 B
  const int myrow = w * 16 + lm;
  __syncthreads();
  #pragma unroll
  for (int t = 0; t < NKL; ++t) mv[(myrow * 4 + lk) * NKL + t] = bv[t];
  __syncthreads();
  if (lk == 0) {
    for (int s2 = 1; s2 < 4; ++s2) {
      for (int t = 0; t < NKL; ++t) {
        unsigned v = mv[(myrow * 4 + s2) * NKL + t];
        if (v >= bv[NKL - 1]) break;   // lane lists sorted ascending
        unsigned x = v;
        #pragma unroll
        for (int q = 0; q < NKL; ++q) {
          unsigned lo = umin32(bv[q], x);
          x = bv[q] < x ? x : bv[q];
          bv[q] = lo;
        }
      }
    }
    unsigned short* cp = cand + (size_t)(b * NN + r0 + myrow) * NKC + ch * NKL;
    #pragma unroll
    for (int t = 0; t < NKL; ++t)
      cp[t] = (unsigned short)((bv[t] & 0x7FFu) + c0);
  }
}

// ---------------------------------------------------------------------------
// Kernel 3 (R11-R16-proven): exact fp32 rescore, one lane per (row, candidate).
// nn overlays cand: exact 64B/row overlay, block-local RAW.
// ---------------------------------------------------------------------------
__global__ __launch_bounds__(256) void rescore_kernel(
    const float* __restrict__ XT, const float* __restrict__ sq,
    unsigned short* __restrict__ cand, int* __restrict__ nn_idx)
{
  __shared__ float dv[8][NKC];
  __shared__ unsigned short di[8][NKC];
  const int tid  = threadIdx.x;
  const int w    = tid >> 6;
  const int lane = tid & 63;
  const int rowL = w * 2 + (lane >> 5);      // 0..7
  const int q    = lane & 31;
  const int row  = blockIdx.x * 8 + rowL;
  const int b = row >> 12, n = row & (NN - 1);
  const float* xt  = XT + (size_t)b * NN * NC;
  const float* sqg = sq + (size_t)b * NN;

  const int j = (int)cand[(size_t)row * NKC + q];
  const float4* cj = (const float4*)(xt + (size_t)j * NC);
  const float4* cn = (const float4*)(xt + (size_t)n * NC);
  float s = 0.f;
  #pragma unroll
  for (int i = 0; i < 16; ++i) {
    float4 a = cn[i], bb = cj[i];
    s = fmaf(a.x, bb.x, s);
    s = fmaf(a.y, bb.y, s);
    s = fmaf(a.z, bb.z, s);
    s = fmaf(a.w, bb.w, s);
  }
  dv[rowL][q] = fmaf(-2.f, s, sqg[j]);
  di[rowL][q] = (unsigned short)j;
  __syncthreads();

  if (tid < 8) {
    const int row2 = blockIdx.x * 8 + tid;
    float bvv[NK]; int bbi[NK];
    #pragma unroll
    for (int p = 0; p < NK; ++p) { bvv[p] = 3.0e38f; bbi[p] = 0; }
    for (int t = 0; t < NKC; ++t) {
      float v = dv[tid][t];
      if (v < bvv[NK - 1]) {
        bvv[NK - 1] = v; bbi[NK - 1] = (int)di[tid][t];
        #pragma unroll
        for (int p = NK - 1; p > 0; --p) {
          if (bvv[p] < bvv[p - 1]) {
            float tv = bvv[p]; bvv[p] = bvv[p - 1]; bvv[p - 1] = tv;
            int   ti = bbi[p]; bbi[p] = bbi[p - 1]; bbi[p - 1] = ti;
          }
        }
      }
    }
    int* np = nn_idx + (size_t)row2 * NK;
    #pragma unroll
    for (int p = 0; p < NK; ++p) np[p] = bbi[p];
  }
}

// ---------------------------------------------------------------------------
// Kernel 4 (R13-R16-proven): gather interleaved P2|Q2 (one u32/lane), softmax.
// ---------------------------------------------------------------------------
__global__ __launch_bounds__(256) void out_kernel(
    const unsigned short* __restrict__ PQb, const int* __restrict__ nn_idx,
    float* __restrict__ out)
{
  __shared__ float ot[TILE][TILE + 1];
  const int bid = blockIdx.x;
  const int b   = bid >> 6;
  const int n0  = (bid & 63) * TILE;
  const int tid = threadIdx.x;
  const int w = tid >> 6, o = tid & 63;

  for (int pi = 0; pi < 16; ++pi) {
    const int p = w * 16 + pi;
    const int n = n0 + p;
    const unsigned short* pqn = PQb + (size_t)(b * NN + n) * 192;
    const float p1b  = bf2f(pqn[o]);
    const int* idxp  = nn_idx + (size_t)(b * NN + n) * NK;
    float p2[NK], q2[NK];
    #pragma unroll
    for (int t = 0; t < NK; ++t) {
      int jn = idxp[t];
      unsigned u = *(const unsigned*)(PQb + (size_t)(b * NN + jn) * 192 + 64 + 2 * o);
      p2[t] = bf2f((unsigned short)(u & 0xFFFFu));
      q2[t] = bf2f((unsigned short)(u >> 16));
    }
    float m = q2[0];
    #pragma unroll
    for (int t = 1; t < NK; ++t) m = fmaxf(m, q2[t]);
    float s = 0.f, num = 0.f;
    #pragma unroll
    for (int t = 0; t < NK; ++t) {
      float e = __expf(q2[t] - m);
      s += e;
      num = fmaf(e, p1b + p2[t], num);
    }
    ot[p][o] = num / s;
  }
  __syncthreads();

  const int oo = tid >> 2, qq = tid & 3;
  float* og = out + (size_t)(b * NO + oo) * NN + n0 + qq * 16;
  #pragma unroll
  for (int i = 0; i < 4; ++i) {
    float4 v;
    v.x = ot[qq * 16 + i * 4 + 0][oo];
    v.y = ot[qq * 16 + i * 4 + 1][oo];
    v.z = ot[qq * 16 + i * 4 + 2][oo];
    v.w = ot[qq * 16 + i * 4 + 3][oo];
    *(float4*)&og[i * 4] = v;
  }
}

// ---------------------------------------------------------------------------
extern "C" void kernel_launch(void* const* d_in, const int* in_sizes, int n_in,
                              void* d_out, int out_size, void* d_ws, size_t ws_size,
                              hipStream_t stream)
{
  const float* x  = (const float*)d_in[0];
  const float* We = (const float*)d_in[1];
  const float* be = (const float*)d_in[2];
  const float* Wa = (const float*)d_in[3];
  float* out = (float*)d_out;

  // workspace: 26.8 MB (< proven 33.69 MB envelope)
  char* ws = (char*)d_ws;
  size_t off = 0;
  float* sq = (float*)(ws + off);                    off += (size_t)NB * NN * 4;        // 128 KB
  unsigned short* PQb = (unsigned short*)(ws + off); off += (size_t)NB * NN * 192 * 2;  // 12.6 MB
  float* XT = (float*)(ws + off);                    off += (size_t)NB * NN * NC * 4;   // 8 MB
  unsigned short* H = (unsigned short*)(ws + off);   off += (size_t)NB * NN * NC * 2;   // 4 MB
  unsigned short* cand = (unsigned short*)(ws + off);                                   // 2 MB
  int* nn = (int*)cand;   // exact per-row 64B overlay; written after reads (block-local)

  dim3 blk(256);
  proj_kernel<<<dim3(NB * (NN / TILE)), blk, 0, stream>>>(x, We, be, Wa, PQb, sq, XT, H);
  knn_kernel<<<dim3(NB * (NN / TILE) * NCHUNK), blk, 0, stream>>>(H, sq, cand);
  rescore_kernel<<<dim3(NB * NN / 8), blk, 0, stream>>>(XT, sq, cand, nn);
  out_kernel<<<dim3(NB * (NN / TILE)), blk, 0, stream>>>(PQb, nn, out);
}